// Round 10
// baseline (161.909 us; speedup 1.0000x reference)
//
#include <hip/hip_runtime.h>
#include <hip/hip_bf16.h>
#include <math.h>

#define B_DIM 8
#define T_DIM 2048
#define D_DIM 1024
#define H_DIM 64
#define SCALE 0.125f

typedef __attribute__((ext_vector_type(8))) short bf16x8;
typedef __attribute__((ext_vector_type(4))) float f32x4;

__device__ __forceinline__ f32x4 mfma16(bf16x8 a, bf16x8 b, f32x4 c) {
    return __builtin_amdgcn_mfma_f32_16x16x32_bf16(a, b, c, 0, 0, 0);
}

__device__ __forceinline__ float rcp_fast(float x) {
    float r;
    asm volatile("v_rcp_f32 %0, %1" : "=v"(r) : "v"(x));
    return r;
}

__device__ __forceinline__ short f2bf(float f) {
    __hip_bfloat16 h = __float2bfloat16(f);
    return *reinterpret_cast<short*>(&h);
}

__device__ __forceinline__ float bf2f(short s) {
    return __uint_as_float(((unsigned int)(unsigned short)s) << 16);
}

__device__ __forceinline__ unsigned pk2(float a, float b) {
    __hip_bfloat162 h = __float22bfloat162_rn(make_float2(a, b));
    return *reinterpret_cast<unsigned*>(&h);
}

__device__ __forceinline__ void cvt4(float4 v, short* dst) {
    __hip_bfloat162 p0 = __float22bfloat162_rn(make_float2(v.x, v.y));
    __hip_bfloat162 p1 = __float22bfloat162_rn(make_float2(v.z, v.w));
    uint2 u;
    u.x = *reinterpret_cast<unsigned int*>(&p0);
    u.y = *reinterpret_cast<unsigned int*>(&p1);
    *reinterpret_cast<uint2*>(dst) = u;  // dst 8B-aligned
}

// asm load: issue pinned where written (volatile), result tied to reg.
__device__ __forceinline__ void gload16(bf16x8& d, const short* p) {
    asm volatile("global_load_dwordx4 %0, %1, off" : "=v"(d) : "v"(p));
}
#define WAITCNT0() do { \
    asm volatile("s_waitcnt vmcnt(0)" ::: "memory"); \
    __builtin_amdgcn_sched_barrier(0); \
} while (0)
#define LGKM0() do { \
    asm volatile("s_waitcnt lgkmcnt(0)" ::: "memory"); \
    __builtin_amdgcn_sched_barrier(0); \
} while (0)
#define RAW_BARRIER() do { \
    __builtin_amdgcn_s_barrier(); \
    __builtin_amdgcn_sched_barrier(0); \
} while (0)

// ---------------------------------------------------------------------------
// prep: transpose-convert W (fp32 [k][h]) -> wt bf16 [m][h][k]. 48 blocks.
// ---------------------------------------------------------------------------
__global__ __launch_bounds__(256) void prep_kernel(
    const float* __restrict__ Wq, const float* __restrict__ Wk,
    const float* __restrict__ Wv, short* __restrict__ wt)
{
    const int blk = blockIdx.x;
    const int tid = threadIdx.x;
    const int m = blk >> 4;
    const int ks = (blk & 15) << 6;
    const float* W = (m == 0) ? Wq : (m == 1) ? Wk : Wv;
    __shared__ float tile[64][68];
#pragma unroll
    for (int t = 0; t < 4; t++) {
        int fi = tid + t * 256;
        int k = fi >> 4, h4 = (fi & 15) << 2;
        *(float4*)&tile[k][h4] = *(const float4*)&W[(size_t)(ks + k) * H_DIM + h4];
    }
    __syncthreads();
    const int h = tid >> 2, seg = (tid & 3) << 4;
    __align__(16) short tmp[16];
#pragma unroll
    for (int kk = 0; kk < 16; kk++) tmp[kk] = f2bf(tile[seg + kk][h]);
    short* dst = wt + ((size_t)m * H_DIM + h) * D_DIM + ks + seg;
    *(bf16x8*)dst = *(bf16x8*)tmp;
    *(bf16x8*)(dst + 8) = *(bf16x8*)(tmp + 8);
}

// ---------------------------------------------------------------------------
// proj: grid 512, block 256. XCD-aligned: batch = bx & 7.
// Outputs: qb,kb bf16 [t][h]; vt bf16 [b][h][t].
// ---------------------------------------------------------------------------
__global__ __launch_bounds__(256) void proj_kernel(
    const float* __restrict__ x, const short* __restrict__ wt,
    short* __restrict__ qb, short* __restrict__ kb, short* __restrict__ vt)
{
    __shared__ short xs[2][32][72];
    __shared__ short wsb[2][192][72];
    __shared__ short ot[32][200];

    const int tid = threadIdx.x;
    const int wv = tid >> 6;
    const int lane = tid & 63;
    const int l15 = lane & 15;
    const int quad = lane >> 4;
    const int t0 = (blockIdx.x & 7) * T_DIM + (blockIdx.x >> 3) * 32;  // XCD-aligned
    const int r0 = (wv & 1) * 16;
    const int c0 = (wv >> 1) * 96;

    f32x4 acc[6];
#pragma unroll
    for (int c = 0; c < 6; c++) acc[c] = (f32x4){0.f, 0.f, 0.f, 0.f};

    float4 xr[2];
    bf16x8 wr[6];
    auto load_tile = [&](int k0) {
#pragma unroll
        for (int t = 0; t < 2; t++) {
            int fi = tid + t * 256;
            int r = fi >> 4, c4 = (fi & 15) << 2;
            xr[t] = *(const float4*)&x[(size_t)(t0 + r) * D_DIM + k0 + c4];
        }
#pragma unroll
        for (int t = 0; t < 6; t++) {
            int fi = tid + t * 256;
            int hh = fi >> 3, sg = (fi & 7) << 3;
            wr[t] = *(const bf16x8*)&wt[(size_t)hh * D_DIM + k0 + sg];
        }
    };
    auto store_tile = [&](int buf) {
#pragma unroll
        for (int t = 0; t < 2; t++) {
            int fi = tid + t * 256;
            int r = fi >> 4, c4 = (fi & 15) << 2;
            cvt4(xr[t], &xs[buf][r][c4]);
        }
#pragma unroll
        for (int t = 0; t < 6; t++) {
            int fi = tid + t * 256;
            int hh = fi >> 3, sg = (fi & 7) << 3;
            *(bf16x8*)&wsb[buf][hh][sg] = wr[t];
        }
    };

    load_tile(0);
    store_tile(0);
    __syncthreads();

    for (int it = 0; it < 16; ++it) {
        const int cur = it & 1;
        if (it < 15) load_tile((it + 1) * 64);
#pragma unroll
        for (int ks = 0; ks < 2; ks++) {
            bf16x8 xa = *(const bf16x8*)&xs[cur][r0 + l15][ks * 32 + quad * 8];
#pragma unroll
            for (int ct = 0; ct < 6; ct++) {
                bf16x8 wb = *(const bf16x8*)&wsb[cur][c0 + ct * 16 + l15][ks * 32 + quad * 8];
                acc[ct] = mfma16(xa, wb, acc[ct]);
            }
        }
        if (it < 15) store_tile(cur ^ 1);
        __syncthreads();
    }

    // epilogue: C-frags -> LDS bf16 tile
#pragma unroll
    for (int ct = 0; ct < 6; ct++)
#pragma unroll
        for (int r = 0; r < 4; r++)
            ot[r0 + quad * 4 + r][c0 + ct * 16 + l15] = f2bf(acc[ct][r]);
    __syncthreads();
#pragma unroll
    for (int t = 0; t < 2; t++) {
        int fi = tid + t * 256;
        int row = fi >> 4, sg = fi & 15;
        bf16x8 v = *(const bf16x8*)&ot[row][sg * 8];
        short* dst = (sg < 8)
            ? &qb[(size_t)(t0 + row) * H_DIM + sg * 8]
            : &kb[(size_t)(t0 + row) * H_DIM + (sg - 8) * 8];
        *(bf16x8*)dst = v;
    }
    {
        const int h = tid >> 2, ts = (tid & 3) << 3;
        const int bb = t0 >> 11;
        const int tloc = (t0 & 2047) + ts;
        __align__(16) short tmp[8];
#pragma unroll
        for (int i = 0; i < 8; i++) tmp[i] = ot[ts + i][128 + h];
        *(bf16x8*)&vt[((size_t)bb * H_DIM + h) * T_DIM + tloc] = *(bf16x8*)tmp;
    }
}

// ---------------------------------------------------------------------------
// stats: Z[k] = sum_{q>=k} exp(s*scale); vt[:,k] *= 1/Z[k].
// r10: grid 512 (8 batches x 64 k-strips of 32 rows), 256 thr / 4 waves.
// 2-3 blocks/CU co-resident -> independent barrier groups overlap each
// other's stalls (r5-r9: 1 block/CU, all 8 waves on one barrier = zero
// overlap; three staging mechanisms all null at ~2250cy/iter).
// Waves: wq = wv&1 (16 k-rows), wpar = wv>>1 (q-tile parity). T14
// reg-staging (2 asm gloads/lane, issue-early/write-late), 2 LDS bufs.
// ---------------------------------------------------------------------------
__global__ __launch_bounds__(256, 2) void stats_kernel(
    const short* __restrict__ qb, const short* __restrict__ kb,
    short* __restrict__ vt)
{
    __shared__ short Qs[2][2][32 * 64];   // 16 KB
    __shared__ float zpart[2][32];
    __shared__ float zfin[32];

    const int tid = threadIdx.x;
    const int wv = tid >> 6;
    const int lane = tid & 63;
    const int l15 = lane & 15;
    const int quad = lane >> 4;
    const int b = blockIdx.x & 7;
    const int sk = blockIdx.x >> 3;        // 0..63, heavy (small sk) first

    const short* qB_ = qb + (size_t)b * T_DIM * H_DIM;
    const short* kB_ = kb + (size_t)b * T_DIM * H_DIM;
    short* vB_ = vt + (size_t)b * H_DIM * T_DIM;

    const int wq = wv & 1;                 // k-row group (16 rows)
    const int wpar = wv >> 1;              // q-tile parity

    const int kw0 = sk * 32 + wq * 16;
    const int nq = 64 - sk;                // 32-row q-tiles
    const int n1 = (nq + 1) >> 1;          // iterations (pairs)

    bf16x8 a0, a1;
    {
        const short* kp = &kB_[(size_t)(kw0 + l15) * H_DIM + quad * 8];
        a0 = *(const bf16x8*)kp;
        a1 = *(const bf16x8*)(kp + 32);
    }
    asm volatile("" :: "v"(a0), "v"(a1));

    bf16x8 sr0, sr1;                        // staged regs (8 VGPR)
    auto issueQ = [&](int it) {
        const int t = min(2 * it + wpar, nq - 1);
        const int qt0 = (sk + t) * 32;
#pragma unroll
        for (int z = 0; z < 2; z++) {
            const int qloc = wq * 16 + z * 8 + (lane >> 3);
            const int u = lane & 7;
            gload16(z == 0 ? sr0 : sr1,
                    &qB_[(size_t)(qt0 + qloc) * H_DIM + (((u - qloc) & 7) << 3)]);
        }
    };
    auto writeQ = [&](int buf) {
#pragma unroll
        for (int z = 0; z < 2; z++) {
            const int cc = wq * 2 + z;
            *(bf16x8*)&Qs[buf][wpar][cc * 512 + lane * 8] = (z == 0) ? sr0 : sr1;
        }
    };

    float acc[4] = {0.f, 0.f, 0.f, 0.f};

    issueQ(0);
    WAITCNT0();
    writeQ(0);
    LGKM0();
    RAW_BARRIER();

    for (int it = 0; it < n1; ++it) {
        if (it + 1 < n1) issueQ(it + 1);    // issue-early

        const int t = 2 * it + wpar;
        if (t < nq) {
            const short* Qb = &Qs[it & 1][wpar][0];
#pragma unroll
            for (int g = 0; g < 2; g++) {
                const int row = g * 16 + l15;
                bf16x8 qf0 = *(const bf16x8*)&Qb[row * 64 + (((quad + l15) & 7) << 3)];
                bf16x8 qf1 = *(const bf16x8*)&Qb[row * 64 + (((4 + quad + l15) & 7) << 3)];
                f32x4 sg = mfma16(a0, qf0, (f32x4){0.f, 0.f, 0.f, 0.f});
                sg = mfma16(a1, qf1, sg);
                if (t == 0) {
#pragma unroll
                    for (int r = 0; r < 4; ++r) {
                        int q = sk * 32 + g * 16 + l15;
                        int k = kw0 + quad * 4 + r;
                        float e = __expf(sg[r] * SCALE);
                        if (q < k) e = 0.f;
                        acc[r] += e;
                    }
                } else {
#pragma unroll
                    for (int r = 0; r < 4; ++r) acc[r] += __expf(sg[r] * SCALE);
                }
            }
        }

        if (it + 1 < n1) {                  // write-late
            WAITCNT0();
            writeQ((it + 1) & 1);
        }
        LGKM0();
        RAW_BARRIER();
    }

#pragma unroll
    for (int r = 0; r < 4; ++r) {
        float z = acc[r];
        z += __shfl_xor(z, 1);
        z += __shfl_xor(z, 2);
        z += __shfl_xor(z, 4);
        z += __shfl_xor(z, 8);
        acc[r] = z;
    }
    if (l15 == 0) {
#pragma unroll
        for (int r = 0; r < 4; ++r)
            zpart[wpar][wq * 16 + quad * 4 + r] = acc[r];
    }
    __syncthreads();
    if (tid < 32) zfin[tid] = rcp_fast(zpart[0][tid] + zpart[1][tid]);
    __syncthreads();

    // scale vt cols [sk*32, +32): 64 h x 32 t, one bf16x8 per thread
    {
        const int h = tid >> 2;
        const int tc = (tid & 3) * 8;
        short* vp = vB_ + (size_t)h * T_DIM + sk * 32 + tc;
        bf16x8 vv = *(bf16x8*)vp;
        __align__(16) short tmp[8];
#pragma unroll
        for (int i = 0; i < 8; i++)
            tmp[i] = f2bf(bf2f(vv[i]) * zfin[tc + i]);
        *(bf16x8*)vp = *(bf16x8*)tmp;
    }
}

// ---------------------------------------------------------------------------
// out: r10: grid 512 (8 batches x 64 q-strips of 32 rows), 256 thr /
// 4 waves, b = bx & 7, s = 63 - (bx>>3) (LPT). 2-3 blocks/CU co-resident
// (LDS 41KB) -> cross-block stall overlap. Waves: wq = wv&1 (16 q-rows),
// wk = wv>>1 (k-tile parity); O pair-summed via osum. T14 reg-staging,
// 4 asm gloads/lane/iter, 2 LDS bufs. Odd k-tile counts: stage clamped,
// compute guarded (wave-uniform).
//
// Swapped-operand QK^T: s = mfma(K, Q) puts q in lanes (l15), k in
// (quad,reg) = the PV A-operand layout; P stays in registers. V read slot
// permutation absorbed in staging addresses. V pre-scaled by 1/Z.
// ---------------------------------------------------------------------------
__global__ __launch_bounds__(256, 2) void out_kernel(
    const short* __restrict__ qb, const short* __restrict__ kb,
    const short* __restrict__ vt, float* __restrict__ out)
{
    __shared__ short Ks[2][2][32 * 64];   // 16 KB
    __shared__ short Vs[2][2][64 * 32];   // 16 KB
    __shared__ float osum[2][16][68];     // 8.7 KB

    const int tid = threadIdx.x;
    const int wv = tid >> 6;
    const int lane = tid & 63;
    const int l15 = lane & 15;
    const int quad = lane >> 4;
    const int b = blockIdx.x & 7;
    const int s = 63 - (blockIdx.x >> 3);  // 0..63, heavy (large s) first

    const short* qB_ = qb + (size_t)b * T_DIM * H_DIM;
    const short* kB_ = kb + (size_t)b * T_DIM * H_DIM;
    const short* vB_ = vt + (size_t)b * H_DIM * T_DIM;

    const int wq = wv & 1;                 // q-row group (16 rows)
    const int wk = wv >> 1;                // k-tile parity
    const int q0w = s * 32 + wq * 16;
    const int n2 = (s + 2) >> 1;           // iterations (pairs of k-tiles)

    const bf16x8 qa0 = *(const bf16x8*)&qB_[(size_t)(q0w + l15) * H_DIM + quad * 8];
    const bf16x8 qa1 = *(const bf16x8*)&qB_[(size_t)(q0w + l15) * H_DIM + 32 + quad * 8];
    asm volatile("" :: "v"(qa0), "v"(qa1));

    f32x4 o0 = {0.f,0.f,0.f,0.f}, o1 = {0.f,0.f,0.f,0.f};
    f32x4 o2 = {0.f,0.f,0.f,0.f}, o3 = {0.f,0.f,0.f,0.f};

    bf16x8 sr[4];                           // staged regs (16 VGPR)
    auto issueKV = [&](int it) {
#pragma unroll
        for (int z = 0; z < 4; z++) {
            const int e = 4 * wv + z;
            const short* src;
            if (e < 8) {
                const int par = e >> 2, c = e & 3;
                const int kt = min(2 * it + par, s);
                const int t = c * 8 + (lane >> 3);
                const int u = lane & 7;
                src = &kB_[(size_t)(kt * 32 + t) * H_DIM + (((u - t) & 7) << 3)];
            } else {
                const int f = e - 8, par = f >> 2, c = f & 3;
                const int kt = min(2 * it + par, s);
                const int h = c * 16 + (lane >> 2);
                const int w = lane & 3;
                src = &vB_[(size_t)h * T_DIM + kt * 32 + (((w - h) & 3) << 3)];
            }
            gload16(sr[z], src);
        }
    };
    auto writeKV = [&](int buf) {
#pragma unroll
        for (int z = 0; z < 4; z++) {
            const int e = 4 * wv + z;
            short* dst;
            if (e < 8) {
                const int par = e >> 2, c = e & 3;
                dst = &Ks[buf][par][c * 512 + lane * 8];
            } else {
                const int f = e - 8, par = f >> 2, c = f & 3;
                dst = &Vs[buf][par][c * 512 + lane * 8];
            }
            *(bf16x8*)dst = sr[z];
        }
    };

    issueKV(0);
    WAITCNT0();
    writeKV(0);
    LGKM0();
    RAW_BARRIER();

    for (int it = 0; it < n2; ++it) {
        if (it + 1 < n2) issueKV(it + 1);   // issue-early

        const int kt = 2 * it + wk;
        if (kt <= s) {
            const int buf = it & 1;
            const short* Kb = &Ks[buf][wk][0];
            const short* Vb = &Vs[buf][wk][0];

            bf16x8 kr[4];
#pragma unroll
            for (int j = 0; j < 4; j++) {
                const int row = (j >> 1) * 16 + l15;
                const int rot = (((j & 1) * 4 + quad) + l15) & 7;
                kr[j] = *(const bf16x8*)&Kb[row * 64 + (rot << 3)];
            }
            f32x4 z4 = {0.f,0.f,0.f,0.f};
            f32x4 s0 = mfma16(kr[0], qa0, z4);
            s0 = mfma16(kr[1], qa1, s0);
            f32x4 s1 = mfma16(kr[2], qa0, z4);
            s1 = mfma16(kr[3], qa1, s1);

            const bool fullT = (kt * 32 + 31) <= q0w;
            const int kg = kt * 32 + quad * 4;
            const int qg = q0w + l15;
            float e0[4], e1[4];
#pragma unroll
            for (int r = 0; r < 4; r++) {
                float a = __expf(s0[r] * SCALE);
                float c = __expf(s1[r] * SCALE);
                if (!fullT) {
                    if (kg + r > qg) a = 0.f;
                    if (kg + 16 + r > qg) c = 0.f;
                }
                e0[r] = a; e1[r] = c;
            }
            bf16x8 pa;
            unsigned* pu = reinterpret_cast<unsigned*>(&pa);
            pu[0] = pk2(e0[0], e0[1]);
            pu[1] = pk2(e0[2], e0[3]);
            pu[2] = pk2(e1[0], e1[1]);
            pu[3] = pk2(e1[2], e1[3]);

#pragma unroll
            for (int jh = 0; jh < 4; jh++) {
                const int h = jh * 16 + l15;
                const int base = h * 32 + ((quad & 1) << 2);
                uint2 lo = *(const uint2*)&Vb[base + ((((quad >> 1) + h) & 3) << 3)];
                uint2 hi = *(const uint2*)&Vb[base + ((((quad >> 1) + 2 + h) & 3) << 3)];
                uint4 all = make_uint4(lo.x, lo.y, hi.x, hi.y);
                bf16x8 vfrag = *reinterpret_cast<bf16x8*>(&all);
                if (jh == 0) o0 = mfma16(pa, vfrag, o0);
                else if (jh == 1) o1 = mfma16(pa, vfrag, o1);
                else if (jh == 2) o2 = mfma16(pa, vfrag, o2);
                else o3 = mfma16(pa, vfrag, o3);
            }
        }

        if (it + 1 < n2) {                  // write-late
            WAITCNT0();
            writeKV((it + 1) & 1);
        }
        LGKM0();
        RAW_BARRIER();
    }

    // pair-sum over k-parity: wk==1 deposit, wk==0 add + store
    if (wk == 1) {
#pragma unroll
        for (int r = 0; r < 4; r++) {
            osum[wq][quad * 4 + r][l15]      = o0[r];
            osum[wq][quad * 4 + r][16 + l15] = o1[r];
            osum[wq][quad * 4 + r][32 + l15] = o2[r];
            osum[wq][quad * 4 + r][48 + l15] = o3[r];
        }
    }
    __syncthreads();
    if (wk == 0) {
#pragma unroll
        for (int r = 0; r < 4; r++) {
            const int row = quad * 4 + r;
            float* dst = &out[(size_t)(b * T_DIM + q0w + row) * H_DIM];
            dst[l15]      = o0[r] + osum[wq][row][l15];
            dst[16 + l15] = o1[r] + osum[wq][row][16 + l15];
            dst[32 + l15] = o2[r] + osum[wq][row][32 + l15];
            dst[48 + l15] = o3[r] + osum[wq][row][48 + l15];
        }
    }
}

// ---------------------------------------------------------------------------
extern "C" void kernel_launch(void* const* d_in, const int* in_sizes, int n_in,
                              void* d_out, int out_size, void* d_ws, size_t ws_size,
                              hipStream_t stream) {
    const float* x  = (const float*)d_in[0];
    const float* Wk = (const float*)d_in[1];
    const float* Wq = (const float*)d_in[2];
    const float* Wv = (const float*)d_in[3];
    float* out = (float*)d_out;

    short* qbuf = (short*)d_ws;                       // 16384*64 bf16
    short* kbuf = qbuf + (size_t)16384 * 64;
    short* vtbuf = kbuf + (size_t)16384 * 64;         // [b][h][t]
    short* wtbuf = vtbuf + (size_t)16384 * 64;        // [3][64][1024]

    prep_kernel<<<48, 256, 0, stream>>>(Wq, Wk, Wv, wtbuf);
    proj_kernel<<<512, 256, 0, stream>>>(x, wtbuf, qbuf, kbuf, vtbuf);
    stats_kernel<<<512, 256, 0, stream>>>(qbuf, kbuf, vtbuf);
    out_kernel<<<512, 256, 0, stream>>>(qbuf, kbuf, vtbuf, out);
}

// Round 12
// 155.578 us; speedup vs baseline: 1.0407x; 1.0407x over previous
//
#include <hip/hip_runtime.h>
#include <hip/hip_bf16.h>
#include <math.h>

#define B_DIM 8
#define T_DIM 2048
#define D_DIM 1024
#define H_DIM 64
#define SCALE 0.125f

typedef __attribute__((ext_vector_type(8))) short bf16x8;
typedef __attribute__((ext_vector_type(4))) float f32x4;

__device__ __forceinline__ f32x4 mfma16(bf16x8 a, bf16x8 b, f32x4 c) {
    return __builtin_amdgcn_mfma_f32_16x16x32_bf16(a, b, c, 0, 0, 0);
}

__device__ __forceinline__ float rcp_fast(float x) {
    float r;
    asm volatile("v_rcp_f32 %0, %1" : "=v"(r) : "v"(x));
    return r;
}

__device__ __forceinline__ short f2bf(float f) {
    __hip_bfloat16 h = __float2bfloat16(f);
    return *reinterpret_cast<short*>(&h);
}

__device__ __forceinline__ float bf2f(short s) {
    return __uint_as_float(((unsigned int)(unsigned short)s) << 16);
}

__device__ __forceinline__ unsigned pk2(float a, float b) {
    __hip_bfloat162 h = __float22bfloat162_rn(make_float2(a, b));
    return *reinterpret_cast<unsigned*>(&h);
}

__device__ __forceinline__ void cvt4(float4 v, short* dst) {
    __hip_bfloat162 p0 = __float22bfloat162_rn(make_float2(v.x, v.y));
    __hip_bfloat162 p1 = __float22bfloat162_rn(make_float2(v.z, v.w));
    uint2 u;
    u.x = *reinterpret_cast<unsigned int*>(&p0);
    u.y = *reinterpret_cast<unsigned int*>(&p1);
    *reinterpret_cast<uint2*>(dst) = u;  // dst 8B-aligned
}

// async global->LDS, 16B/lane, dest = wave-uniform base + lane*16 (linear)
typedef __attribute__((address_space(1))) const void gas_void;
typedef __attribute__((address_space(3))) void las_void;
__device__ __forceinline__ void gl_lds16(const short* g, short* l) {
    __builtin_amdgcn_global_load_lds((gas_void*)g, (las_void*)l, 16, 0, 0);
}

// counted per-wave vmcnt (T4): literal only. sched_barrier stops hoisting.
#define WAITV(lit) do { \
    asm volatile("s_waitcnt vmcnt(" #lit ")" ::: "memory"); \
    __builtin_amdgcn_sched_barrier(0); \
} while (0)
#define RAW_BARRIER() do { \
    __builtin_amdgcn_s_barrier(); \
    __builtin_amdgcn_sched_barrier(0); \
} while (0)

// ---------------------------------------------------------------------------
// prep: transpose-convert W (fp32 [k][h]) -> wt bf16 [m][h][k]. 48 blocks.
// ---------------------------------------------------------------------------
__global__ __launch_bounds__(256) void prep_kernel(
    const float* __restrict__ Wq, const float* __restrict__ Wk,
    const float* __restrict__ Wv, short* __restrict__ wt)
{
    const int blk = blockIdx.x;
    const int tid = threadIdx.x;
    const int m = blk >> 4;
    const int ks = (blk & 15) << 6;
    const float* W = (m == 0) ? Wq : (m == 1) ? Wk : Wv;
    __shared__ float tile[64][68];
#pragma unroll
    for (int t = 0; t < 4; t++) {
        int fi = tid + t * 256;
        int k = fi >> 4, h4 = (fi & 15) << 2;
        *(float4*)&tile[k][h4] = *(const float4*)&W[(size_t)(ks + k) * H_DIM + h4];
    }
    __syncthreads();
    const int h = tid >> 2, seg = (tid & 3) << 4;
    __align__(16) short tmp[16];
#pragma unroll
    for (int kk = 0; kk < 16; kk++) tmp[kk] = f2bf(tile[seg + kk][h]);
    short* dst = wt + ((size_t)m * H_DIM + h) * D_DIM + ks + seg;
    *(bf16x8*)dst = *(bf16x8*)tmp;
    *(bf16x8*)(dst + 8) = *(bf16x8*)(tmp + 8);
}

// ---------------------------------------------------------------------------
// proj: grid 512, block 256. XCD-aligned: batch = bx & 7, so batch-b rows
// are written from XCD-b CUs (stats/out read batch b pinned to XCD b).
// Outputs: qb,kb bf16 [t][h]; vt bf16 [b][h][t].
// ---------------------------------------------------------------------------
__global__ __launch_bounds__(256) void proj_kernel(
    const float* __restrict__ x, const short* __restrict__ wt,
    short* __restrict__ qb, short* __restrict__ kb, short* __restrict__ vt)
{
    __shared__ short xs[2][32][72];
    __shared__ short wsb[2][192][72];
    __shared__ short ot[32][200];

    const int tid = threadIdx.x;
    const int wv = tid >> 6;
    const int lane = tid & 63;
    const int l15 = lane & 15;
    const int quad = lane >> 4;
    const int t0 = (blockIdx.x & 7) * T_DIM + (blockIdx.x >> 3) * 32;  // XCD-aligned
    const int r0 = (wv & 1) * 16;
    const int c0 = (wv >> 1) * 96;

    f32x4 acc[6];
#pragma unroll
    for (int c = 0; c < 6; c++) acc[c] = (f32x4){0.f, 0.f, 0.f, 0.f};

    float4 xr[2];
    bf16x8 wr[6];
    auto load_tile = [&](int k0) {
#pragma unroll
        for (int t = 0; t < 2; t++) {
            int fi = tid + t * 256;
            int r = fi >> 4, c4 = (fi & 15) << 2;
            xr[t] = *(const float4*)&x[(size_t)(t0 + r) * D_DIM + k0 + c4];
        }
#pragma unroll
        for (int t = 0; t < 6; t++) {
            int fi = tid + t * 256;
            int hh = fi >> 3, sg = (fi & 7) << 3;
            wr[t] = *(const bf16x8*)&wt[(size_t)hh * D_DIM + k0 + sg];
        }
    };
    auto store_tile = [&](int buf) {
#pragma unroll
        for (int t = 0; t < 2; t++) {
            int fi = tid + t * 256;
            int r = fi >> 4, c4 = (fi & 15) << 2;
            cvt4(xr[t], &xs[buf][r][c4]);
        }
#pragma unroll
        for (int t = 0; t < 6; t++) {
            int fi = tid + t * 256;
            int hh = fi >> 3, sg = (fi & 7) << 3;
            *(bf16x8*)&wsb[buf][hh][sg] = wr[t];
        }
    };

    load_tile(0);
    store_tile(0);
    __syncthreads();

    for (int it = 0; it < 16; ++it) {
        const int cur = it & 1;
        if (it < 15) load_tile((it + 1) * 64);
#pragma unroll
        for (int ks = 0; ks < 2; ks++) {
            bf16x8 xa = *(const bf16x8*)&xs[cur][r0 + l15][ks * 32 + quad * 8];
#pragma unroll
            for (int ct = 0; ct < 6; ct++) {
                bf16x8 wb = *(const bf16x8*)&wsb[cur][c0 + ct * 16 + l15][ks * 32 + quad * 8];
                acc[ct] = mfma16(xa, wb, acc[ct]);
            }
        }
        if (it < 15) store_tile(cur ^ 1);
        __syncthreads();
    }

    // epilogue: C-frags -> LDS bf16 tile
#pragma unroll
    for (int ct = 0; ct < 6; ct++)
#pragma unroll
        for (int r = 0; r < 4; r++)
            ot[r0 + quad * 4 + r][c0 + ct * 16 + l15] = f2bf(acc[ct][r]);
    __syncthreads();
#pragma unroll
    for (int t = 0; t < 2; t++) {
        int fi = tid + t * 256;
        int row = fi >> 4, sg = fi & 15;
        bf16x8 v = *(const bf16x8*)&ot[row][sg * 8];
        short* dst = (sg < 8)
            ? &qb[(size_t)(t0 + row) * H_DIM + sg * 8]
            : &kb[(size_t)(t0 + row) * H_DIM + (sg - 8) * 8];
        *(bf16x8*)dst = v;
    }
    {
        const int h = tid >> 2, ts = (tid & 3) << 3;
        const int bb = t0 >> 11;
        const int tloc = (t0 & 2047) + ts;
        __align__(16) short tmp[8];
#pragma unroll
        for (int i = 0; i < 8; i++) tmp[i] = ot[ts + i][128 + h];
        *(bf16x8*)&vt[((size_t)bb * H_DIM + h) * T_DIM + tloc] = *(bf16x8*)tmp;
    }
}

// ---------------------------------------------------------------------------
// stats: Z[k] = sum_{q>=k} exp(s*scale); vt[:,k] *= 1/Z[k]. grid 256
// (8 batches x 32 k-blocks of 64 rows), 512 thr / 8 waves, b = bx & 7.
//
// r12: QUAD iterations -- 4 q-tiles per barrier (was 2 in r7). r7/r8
// proved depth-2/4 counted pipelines are correct AND perf-invariant ->
// the ~2300cy/iter is fixed per-barrier overhead; halving barrier count
// is the untried divisor. 4 LDS buffers (r7 distance analysis), 2 stage
// instr/wave/iter, WAITV(4) = tile-it chunks landed, it+1/it+2 in flight.
// Each wave computes its parity's TWO tiles per iter (j=0,1).
// ---------------------------------------------------------------------------
__global__ __launch_bounds__(512, 2) void stats_kernel(
    const short* __restrict__ qb, const short* __restrict__ kb,
    short* __restrict__ vt)
{
    __shared__ short Qs[4][4][32 * 64];   // 64 KB
    __shared__ float zpart[2][64];
    __shared__ float zfin[64];

    const int tid = threadIdx.x;
    const int wv = tid >> 6;
    const int lane = tid & 63;
    const int l15 = lane & 15;
    const int quad = lane >> 4;
    const int b = blockIdx.x & 7;
    const int kbk = blockIdx.x >> 3;       // 0..31, heavy first

    const short* qB_ = qb + (size_t)b * T_DIM * H_DIM;
    const short* kB_ = kb + (size_t)b * T_DIM * H_DIM;
    short* vB_ = vt + (size_t)b * H_DIM * T_DIM;

    const int wq = wv & 3;
    const int wpar = wv >> 2;              // 0/1

    const int kw0 = kbk * 64 + wq * 16;
    const int nt = 64 - 2 * kbk;           // 32-row q-tiles
    const int n1 = (nt + 3) >> 2;          // quad iterations

    bf16x8 a0, a1;
    {
        const short* kp = &kB_[(size_t)(kw0 + l15) * H_DIM + quad * 8];
        a0 = *(const bf16x8*)kp;
        a1 = *(const bf16x8*)(kp + 32);
    }
    asm volatile("" :: "v"(a0), "v"(a1));  // materialize before staging

    // stage one quad (4 tiles x 4KB = 16 chunks); 2 instr/wave: e = 2*wv+z
    auto stage = [&](int it, int buf) {
#pragma unroll
        for (int z = 0; z < 2; z++) {
            const int e = 2 * wv + z;
            const int p = e >> 2, c = e & 3;
            const int tq = min(4 * it + p, nt - 1);
            const int t = c * 8 + (lane >> 3);
            const int u = lane & 7;
            gl_lds16(&qB_[(size_t)(kbk * 64 + tq * 32 + t) * H_DIM + (((u - t) & 7) << 3)],
                     &Qs[buf][p][c * 512]);
        }
    };

    float acc[4] = {0.f, 0.f, 0.f, 0.f};

    stage(0, 0);
    stage(min(1, n1 - 1), 1);
    for (int it = 0; it < n1; ++it) {
        stage(min(it + 2, n1 - 1), (it + 2) & 3);
        WAITV(4);          // 6 outstanding -> 4: tile-it chunks landed
        RAW_BARRIER();
        const int buf = it & 3;
#pragma unroll
        for (int j = 0; j < 2; j++) {
            const int tq = 4 * it + 2 * j + wpar;
            if (tq < nt) {
                const short* Qb = &Qs[buf][2 * j + wpar][0];
#pragma unroll
                for (int g = 0; g < 2; g++) {
                    const int row = g * 16 + l15;
                    bf16x8 qf0 = *(const bf16x8*)&Qb[row * 64 + (((quad + l15) & 7) << 3)];
                    bf16x8 qf1 = *(const bf16x8*)&Qb[row * 64 + (((4 + quad + l15) & 7) << 3)];
                    f32x4 sg = mfma16(a0, qf0, (f32x4){0.f, 0.f, 0.f, 0.f});
                    sg = mfma16(a1, qf1, sg);
                    if (it == 0 && j == 0) {   // tiles 0,1: causal edge
#pragma unroll
                        for (int r = 0; r < 4; ++r) {
                            int q = kbk * 64 + tq * 32 + g * 16 + l15;
                            int k = kw0 + quad * 4 + r;
                            float e = __expf(sg[r] * SCALE);
                            if (q < k) e = 0.f;
                            acc[r] += e;
                        }
                    } else {
#pragma unroll
                        for (int r = 0; r < 4; ++r) acc[r] += __expf(sg[r] * SCALE);
                    }
                }
            }
        }
    }

#pragma unroll
    for (int r = 0; r < 4; ++r) {
        float z = acc[r];
        z += __shfl_xor(z, 1);
        z += __shfl_xor(z, 2);
        z += __shfl_xor(z, 4);
        z += __shfl_xor(z, 8);
        acc[r] = z;
    }
    if (l15 == 0) {
#pragma unroll
        for (int r = 0; r < 4; ++r)
            zpart[wpar][wq * 16 + quad * 4 + r] = acc[r];
    }
    __syncthreads();   // drains tail dummy stages too
    if (tid < 64) zfin[tid] = rcp_fast(zpart[0][tid] + zpart[1][tid]);
    __syncthreads();

    // scale vt cols [kbk*64, +64): 64h x 64t, one bf16x8 per thread
    {
        const int h = tid >> 3;
        const int tc = (tid & 7) * 8;
        short* vp = vB_ + (size_t)h * T_DIM + kbk * 64 + tc;
        bf16x8 vv = *(bf16x8*)vp;
        __align__(16) short tmp[8];
#pragma unroll
        for (int i = 0; i < 8; i++)
            tmp[i] = f2bf(bf2f(vv[i]) * zfin[tc + i]);
        *(bf16x8*)vp = *(bf16x8*)tmp;
    }
}

// ---------------------------------------------------------------------------
// out: grid 256 (8 batches x 32 q-blocks of 64 rows), 512 thr / 8 waves,
// b = bx & 7, qbk = 31 - (bx>>3) (LPT). Waves 0-3 own 16 q-rows each /
// even k-tiles; waves 4-7 same rows / odd tiles; O pair-summed via LDS.
//
// r12: QUAD iterations -- 4 k-tiles per barrier (see stats comment).
// 4 LDS buffers, 4 stage instr/wave/iter, WAITV(8) (12 outstanding -> 8:
// tile-it's 4 chunks landed). Each wave computes 2 k-tiles per iter.
//
// Swapped-operand QK^T: s = mfma(K, Q) puts q in lanes (l15), k in
// (quad,reg) = the PV A-operand layout; P stays in registers. The A-slot
// k-permutation is absorbed into the V staging addresses. V pre-scaled
// by 1/Z, so P = exp(s*scale) directly.
// ---------------------------------------------------------------------------
__global__ __launch_bounds__(512, 2) void out_kernel(
    const short* __restrict__ qb, const short* __restrict__ kb,
    const short* __restrict__ vt, float* __restrict__ out)
{
    __shared__ short Ks[4][4][32 * 64];   // 64 KB
    __shared__ short Vs[4][4][64 * 32];   // 64 KB
    __shared__ float osum[4][16][68];     // 17.4 KB -> 145.4 KB total

    const int tid = threadIdx.x;
    const int wv = tid >> 6;
    const int lane = tid & 63;
    const int l15 = lane & 15;
    const int quad = lane >> 4;
    const int b = blockIdx.x & 7;
    const int qbk = 31 - (blockIdx.x >> 3);   // heavy (large qbk) first

    const short* qB_ = qb + (size_t)b * T_DIM * H_DIM;
    const short* kB_ = kb + (size_t)b * T_DIM * H_DIM;
    const short* vB_ = vt + (size_t)b * H_DIM * T_DIM;

    const int wq = wv & 3;
    const int wk = wv >> 2;                 // k-tile parity
    const int q0w = qbk * 64 + wq * 16;
    const int ntk = 2 * qbk + 2;            // 32-row k-tiles
    const int n2 = (ntk + 3) >> 2;          // quad iterations

    const bf16x8 qa0 = *(const bf16x8*)&qB_[(size_t)(q0w + l15) * H_DIM + quad * 8];
    const bf16x8 qa1 = *(const bf16x8*)&qB_[(size_t)(q0w + l15) * H_DIM + 32 + quad * 8];
    asm volatile("" :: "v"(qa0), "v"(qa1));

    f32x4 o0 = {0.f,0.f,0.f,0.f}, o1 = {0.f,0.f,0.f,0.f};
    f32x4 o2 = {0.f,0.f,0.f,0.f}, o3 = {0.f,0.f,0.f,0.f};

    // stage one quad (4 K-tiles 16KB + 4 V-tiles 16KB = 32 chunks);
    // 4 instr/wave: e = 4*wv+z in 0..31
    auto stageKV = [&](int it, int buf) {
#pragma unroll
        for (int z = 0; z < 4; z++) {
            const int e = 4 * wv + z;
            if (e < 16) {
                const int p = e >> 2, c = e & 3;
                const int kt = min(4 * it + p, ntk - 1);
                const int t = c * 8 + (lane >> 3);
                const int u = lane & 7;
                gl_lds16(&kB_[(size_t)(kt * 32 + t) * H_DIM + (((u - t) & 7) << 3)],
                         &Ks[buf][p][c * 512]);
            } else {
                const int f = e - 16, p = f >> 2, c = f & 3;
                const int kt = min(4 * it + p, ntk - 1);
                const int h = c * 16 + (lane >> 2);
                const int w = lane & 3;
                gl_lds16(&vB_[(size_t)h * T_DIM + kt * 32 + (((w - h) & 3) << 3)],
                         &Vs[buf][p][c * 512]);
            }
        }
    };

    stageKV(0, 0);
    stageKV(min(1, n2 - 1), 1);
    for (int it = 0; it < n2; ++it) {
        stageKV(min(it + 2, n2 - 1), (it + 2) & 3);
        WAITV(8);          // 12 outstanding -> 8: tile-it's 4 chunks landed
        RAW_BARRIER();
        const int buf = it & 3;
#pragma unroll
        for (int j = 0; j < 2; j++) {
            const int kt = 4 * it + 2 * j + wk;
            if (kt < ntk) {
                const short* Kb = &Ks[buf][2 * j + wk][0];
                const short* Vb = &Vs[buf][2 * j + wk][0];

                bf16x8 kr[4];
#pragma unroll
                for (int jj = 0; jj < 4; jj++) {
                    const int row = (jj >> 1) * 16 + l15;
                    const int rot = (((jj & 1) * 4 + quad) + l15) & 7;
                    kr[jj] = *(const bf16x8*)&Kb[row * 64 + (rot << 3)];
                }
                f32x4 z4 = {0.f,0.f,0.f,0.f};
                f32x4 s0 = mfma16(kr[0], qa0, z4);
                s0 = mfma16(kr[1], qa1, s0);
                f32x4 s1 = mfma16(kr[2], qa0, z4);
                s1 = mfma16(kr[3], qa1, s1);

                const bool fullT = (kt * 32 + 31) <= q0w;
                const int kg = kt * 32 + quad * 4;
                const int qg = q0w + l15;
                float e0[4], e1[4];
#pragma unroll
                for (int r = 0; r < 4; r++) {
                    float a = __expf(s0[r] * SCALE);
                    float c = __expf(s1[r] * SCALE);
                    if (!fullT) {
                        if (kg + r > qg) a = 0.f;
                        if (kg + 16 + r > qg) c = 0.f;
                    }
                    e0[r] = a; e1[r] = c;
                }
                bf16x8 pa;
                unsigned* pu = reinterpret_cast<unsigned*>(&pa);
                pu[0] = pk2(e0[0], e0[1]);
                pu[1] = pk2(e0[2], e0[3]);
                pu[2] = pk2(e1[0], e1[1]);
                pu[3] = pk2(e1[2], e1[3]);

#pragma unroll
                for (int jh = 0; jh < 4; jh++) {
                    const int h = jh * 16 + l15;
                    const int base = h * 32 + ((quad & 1) << 2);
                    uint2 lo = *(const uint2*)&Vb[base + ((((quad >> 1) + h) & 3) << 3)];
                    uint2 hi = *(const uint2*)&Vb[base + ((((quad >> 1) + 2 + h) & 3) << 3)];
                    uint4 all = make_uint4(lo.x, lo.y, hi.x, hi.y);
                    bf16x8 vfrag = *reinterpret_cast<bf16x8*>(&all);
                    if (jh == 0) o0 = mfma16(pa, vfrag, o0);
                    else if (jh == 1) o1 = mfma16(pa, vfrag, o1);
                    else if (jh == 2) o2 = mfma16(pa, vfrag, o2);
                    else o3 = mfma16(pa, vfrag, o3);
                }
            }
        }
    }
    __syncthreads();   // drains tail dummy stages

    // pair-sum: odd-parity waves deposit, even-parity waves add + store
    if (wk == 1) {
#pragma unroll
        for (int r = 0; r < 4; r++) {
            osum[wq][quad * 4 + r][l15]      = o0[r];
            osum[wq][quad * 4 + r][16 + l15] = o1[r];
            osum[wq][quad * 4 + r][32 + l15] = o2[r];
            osum[wq][quad * 4 + r][48 + l15] = o3[r];
        }
    }
    __syncthreads();
    if (wk == 0) {
#pragma unroll
        for (int r = 0; r < 4; r++) {
            const int row = quad * 4 + r;
            float* dst = &out[(size_t)(b * T_DIM + q0w + row) * H_DIM];
            dst[l15]      = o0[r] + osum[wq][row][l15];
            dst[16 + l15] = o1[r] + osum[wq][row][16 + l15];
            dst[32 + l15] = o2[r] + osum[wq][row][32 + l15];
            dst[48 + l15] = o3[r] + osum[wq][row][48 + l15];
        }
    }
}

// ---------------------------------------------------------------------------
extern "C" void kernel_launch(void* const* d_in, const int* in_sizes, int n_in,
                              void* d_out, int out_size, void* d_ws, size_t ws_size,
                              hipStream_t stream) {
    const float* x  = (const float*)d_in[0];
    const float* Wk = (const float*)d_in[1];
    const float* Wq = (const float*)d_in[2];
    const float* Wv = (const float*)d_in[3];
    float* out = (float*)d_out;

    short* qbuf = (short*)d_ws;                       // 16384*64 bf16
    short* kbuf = qbuf + (size_t)16384 * 64;
    short* vtbuf = kbuf + (size_t)16384 * 64;         // [b][h][t]
    short* wtbuf = vtbuf + (size_t)16384 * 64;        // [3][64][1024]

    prep_kernel<<<48, 256, 0, stream>>>(Wq, Wk, Wv, wtbuf);
    proj_kernel<<<512, 256, 0, stream>>>(x, wtbuf, qbuf, kbuf, vtbuf);
    stats_kernel<<<256, 512, 0, stream>>>(qbuf, kbuf, vtbuf);
    out_kernel<<<256, 512, 0, stream>>>(qbuf, kbuf, vtbuf, out);
}